// Round 13
// baseline (2333.429 us; speedup 1.0000x reference)
//
#include <hip/hip_runtime.h>
#include <stdint.h>

#define NN 50000
#define NE 1600000

typedef _Float16 f16;
typedef __attribute__((ext_vector_type(8))) _Float16 h8;
typedef __attribute__((ext_vector_type(4))) _Float16 h4v;
typedef __attribute__((ext_vector_type(4))) float f32x4;
typedef __attribute__((ext_vector_type(2))) float f32x2;

union PackU { unsigned int u; f16 h[2]; };
union Pack4 { uint2 v; f16 h[4]; };

__device__ __forceinline__ void storev(float* p, float v) { *p = v; }
__device__ __forceinline__ void storev(f16* p, float v) { *p = (f16)v; }

__device__ __forceinline__ unsigned char f2fp8(float v) {
    int pk = __builtin_amdgcn_cvt_pk_fp8_f32(v, v, 0, false);
    return (unsigned char)(pk & 0xff);
}

// ---------------------------------------------------------------------------
// Preprocessing
// ---------------------------------------------------------------------------
__global__ __launch_bounds__(256) void zero_int_kernel(int* __restrict__ p, int n) {
    int i = blockIdx.x * 256 + threadIdx.x;
    if (i < n) p[i] = 0;
}

__global__ __launch_bounds__(256) void count_kernel(const int* __restrict__ dst,
                                                    int* __restrict__ deg, int nE) {
    int e = blockIdx.x * 256 + threadIdx.x;
    if (e < nE) atomicAdd(&deg[dst[e]], 1);
}

__global__ __launch_bounds__(256) void dinv_kernel(const int* __restrict__ deg,
                                                   float* __restrict__ dinv, int n) {
    int i = blockIdx.x * 256 + threadIdx.x;
    if (i < n) dinv[i] = rsqrtf((float)deg[i] + 1.0f);
}

// Parallel 3-phase exclusive scan over 50000 ints (196 blocks of 256).
__global__ __launch_bounds__(256) void scan1_kernel(const int* __restrict__ cnt,
                                                    int* __restrict__ rs,
                                                    int* __restrict__ bsum, int n) {
    __shared__ int sm[256];
    int b = blockIdx.x, t = threadIdx.x, i = b * 256 + t;
    int v = (i < n) ? cnt[i] : 0;
    sm[t] = v;
    __syncthreads();
    for (int off = 1; off < 256; off <<= 1) {
        int x = 0;
        if (t >= off) x = sm[t - off];
        __syncthreads();
        if (t >= off) sm[t] += x;
        __syncthreads();
    }
    if (i < n) rs[i] = sm[t] - v;  // block-local exclusive
    if (t == 255) bsum[b] = sm[255];
}

__global__ __launch_bounds__(256) void scan2_kernel(int* __restrict__ bsum,
                                                    int* __restrict__ rs, int nb, int n) {
    __shared__ int sm[256];
    int t = threadIdx.x;
    int v = (t < nb) ? bsum[t] : 0;
    sm[t] = v;
    __syncthreads();
    for (int off = 1; off < 256; off <<= 1) {
        int x = 0;
        if (t >= off) x = sm[t - off];
        __syncthreads();
        if (t >= off) sm[t] += x;
        __syncthreads();
    }
    if (t < nb) bsum[t] = sm[t] - v;  // exclusive block offsets
    if (t == 255) rs[n] = sm[255];    // grand total (= nE)
}

__global__ __launch_bounds__(256) void scan3_kernel(int* __restrict__ rs,
                                                    const int* __restrict__ bsum, int n) {
    int i = blockIdx.x * 256 + threadIdx.x;
    if (i < n) rs[i] += bsum[blockIdx.x];
}

__global__ __launch_bounds__(256) void fill_kernel(const int* __restrict__ src,
                                                   const int* __restrict__ dst,
                                                   const int* __restrict__ rs,
                                                   int* __restrict__ cur,
                                                   int* __restrict__ csr, int nE) {
    int e = blockIdx.x * 256 + threadIdx.x;
    if (e < nE) {
        int d = dst[e];
        int p = rs[d] + atomicAdd(&cur[d], 1);
        csr[p] = src[e];
    }
}

// w1p[k*4 + {0,1,2,3}] = {W1[0][k], W1[1][k], W1[2][k], b1[k]}
__global__ __launch_bounds__(256) void pack_w1_kernel(const float* __restrict__ W1,
                                                      const float* __restrict__ b1,
                                                      float* __restrict__ w1p) {
    int k = blockIdx.x * 256 + threadIdx.x;
    if (k < 4096) {
        w1p[k * 4 + 0] = W1[k];
        w1p[k * 4 + 1] = W1[4096 + k];
        w1p[k * 4 + 2] = W1[8192 + k];
        w1p[k * 4 + 3] = b1[k];
    }
}

// Transpose-convert: Wt[n][k] = f16(W[k][n]); K, N multiples of 32.
__global__ __launch_bounds__(256) void tconv_kernel(const float* __restrict__ W,
                                                    f16* __restrict__ Wt,
                                                    int K, int N) {
    __shared__ float tile[32][33];
    int kb = blockIdx.y * 32, nb = blockIdx.x * 32;
    int tx = threadIdx.x & 31, ty = threadIdx.x >> 5;
    for (int r = ty; r < 32; r += 8)
        tile[r][tx] = W[(size_t)(kb + r) * N + nb + tx];
    __syncthreads();
    for (int r = ty; r < 32; r += 8)
        Wt[(size_t)(nb + r) * K + kb + tx] = (f16)tile[tx][r];
}

// ---------------------------------------------------------------------------
// fp32-input aggregation (widths 3, 64, 16)
// ---------------------------------------------------------------------------
template <int F, int TPN, bool RELU, bool BIAS, typename OutT>
__global__ __launch_bounds__(256) void agg_kernel(const float* __restrict__ t,
                                                  const float* __restrict__ dinv,
                                                  const int* __restrict__ rs,
                                                  const int* __restrict__ csr,
                                                  const float* __restrict__ bias,
                                                  OutT* __restrict__ out, int out_ld,
                                                  int nNodes) {
    constexpr int NPB = 256 / TPN;
    constexpr int C   = F / TPN;
    static_assert(TPN * C == F, "F must be TPN*C");
    int node = blockIdx.x * NPB + (int)threadIdx.x / TPN;
    if (node >= nNodes) return;
    int lane = (int)threadIdx.x % TPN;

    float acc[C];
#pragma unroll
    for (int c = 0; c < C; ++c) acc[c] = 0.f;

    int e0 = rs[node], e1 = rs[node + 1];
    for (int e = e0; e < e1; ++e) {
        int s = csr[e];
        float w = dinv[s];
        const float* tr = t + (size_t)s * F;
#pragma unroll
        for (int c = 0; c < C; ++c) acc[c] += w * tr[lane + c * TPN];
    }
    float di = dinv[node];
    const float* ti = t + (size_t)node * F;
    OutT* oi = out + (size_t)node * out_ld;
#pragma unroll
    for (int c = 0; c < C; ++c) {
        int col = lane + c * TPN;
        float v = di * acc[c] + di * di * ti[col];
        if (BIAS) v += bias[col];
        if (RELU) v = fmaxf(v, 0.f);
        storev(oi + col, v);
    }
}

// ---------------------------------------------------------------------------
// fp8 aggregation over a 64-col slice: 16 lanes/node (16 nodes/block), each
// lane owns 4 consecutive cols via one uint load (4 fp8 e4m3). 64-col slice
// working set = 3.2 MB -> fits per-XCD L2 (4 MB), unlike the 12.8 MB 256-col
// slice which thrashed to L3 (round-12 analysis). csr reads nontemporal
// (streamed once; don't evict the slice). in_ld = source row stride (fp8),
// bias/out pre-offset by the slice base; out stride out_ld (f16).
// ---------------------------------------------------------------------------
template <bool RELU>
__global__ __launch_bounds__(256) void agg_fp8_64(const unsigned char* __restrict__ t,
                                                  int in_ld,
                                                  const float* __restrict__ dinv,
                                                  const int* __restrict__ rs,
                                                  const int* __restrict__ csr,
                                                  const float* __restrict__ bias,
                                                  f16* __restrict__ out,
                                                  int out_ld, int nNodes) {
    int node = blockIdx.x * 16 + ((int)threadIdx.x >> 4);
    if (node >= nNodes) return;
    int lane = (int)threadIdx.x & 15;

    float acc0 = 0.f, acc1 = 0.f, acc2 = 0.f, acc3 = 0.f;
    int e0 = rs[node], e1 = rs[node + 1];
    int e = e0;
    for (; e + 1 < e1; e += 2) {
        int s0 = __builtin_nontemporal_load(csr + e);
        int s1 = __builtin_nontemporal_load(csr + e + 1);
        float w0 = dinv[s0], w1 = dinv[s1];
        unsigned int u0 = ((const unsigned int*)(t + (size_t)s0 * in_ld))[lane];
        unsigned int u1 = ((const unsigned int*)(t + (size_t)s1 * in_ld))[lane];
        f32x2 l0 = __builtin_amdgcn_cvt_pk_f32_fp8((int)u0, false);
        f32x2 h0 = __builtin_amdgcn_cvt_pk_f32_fp8((int)u0, true);
        f32x2 l1 = __builtin_amdgcn_cvt_pk_f32_fp8((int)u1, false);
        f32x2 h1 = __builtin_amdgcn_cvt_pk_f32_fp8((int)u1, true);
        acc0 += w0 * l0.x + w1 * l1.x;
        acc1 += w0 * l0.y + w1 * l1.y;
        acc2 += w0 * h0.x + w1 * h1.x;
        acc3 += w0 * h0.y + w1 * h1.y;
    }
    if (e < e1) {
        int s0 = __builtin_nontemporal_load(csr + e);
        float w0 = dinv[s0];
        unsigned int u0 = ((const unsigned int*)(t + (size_t)s0 * in_ld))[lane];
        f32x2 l0 = __builtin_amdgcn_cvt_pk_f32_fp8((int)u0, false);
        f32x2 h0 = __builtin_amdgcn_cvt_pk_f32_fp8((int)u0, true);
        acc0 += w0 * l0.x;
        acc1 += w0 * l0.y;
        acc2 += w0 * h0.x;
        acc3 += w0 * h0.y;
    }
    float di = dinv[node], di2 = di * di;
    unsigned int us = ((const unsigned int*)(t + (size_t)node * in_ld))[lane];
    f32x2 sl = __builtin_amdgcn_cvt_pk_f32_fp8((int)us, false);
    f32x2 sh = __builtin_amdgcn_cvt_pk_f32_fp8((int)us, true);
    float4 b = *(const float4*)(bias + 4 * lane);
    float v0 = di * acc0 + di2 * sl.x + b.x;
    float v1 = di * acc1 + di2 * sl.y + b.y;
    float v2 = di * acc2 + di2 * sh.x + b.z;
    float v3 = di * acc3 + di2 * sh.y + b.w;
    if (RELU) {
        v0 = fmaxf(v0, 0.f); v1 = fmaxf(v1, 0.f);
        v2 = fmaxf(v2, 0.f); v3 = fmaxf(v3, 0.f);
    }
    Pack4 pk;
    pk.h[0] = (f16)v0; pk.h[1] = (f16)v1; pk.h[2] = (f16)v2; pk.h[3] = (f16)v3;
    *(uint2*)(out + (size_t)node * out_ld + 4 * lane) = pk.v;
}

// ---------------------------------------------------------------------------
// MFMA GEMM kernels. LDS row stride 40 f16 = 80 B (16 B-aligned).
// Fragments: A[m=lane&15][k=(lane>>4)*8+j]; B^T rows; C/D col=lane&15,
// row=(lane>>4)*4+reg.
// ---------------------------------------------------------------------------
#define LDSTR 40

// Fused layer1+2 (round-11 structure — best measured, 752 us; round-12's
// B-direct-from-L2 variant regressed to 1327 us and was reverted).
// 512 threads = 8 waves (2m x 4n, each 64m x 64n, 16 MFMA/K-step).
// 128m x 256n tile. A-tile (h1 = relu(aggx@W1+b1) f16) computed on the fly.
// Output fp8 into t2[NN][1024].
__global__ __launch_bounds__(512, 4) void gemm12_mfma4(const float* __restrict__ aggx,
                                                       const float* __restrict__ w1p,
                                                       const f16* __restrict__ Bt,
                                                       unsigned char* __restrict__ t2) {
    __shared__ f16 As[128 * LDSTR] __attribute__((aligned(16)));
    __shared__ f16 Bs[256 * LDSTR] __attribute__((aligned(16)));
    int tid = threadIdx.x;
    int m0  = blockIdx.x * 128;
    int n0c = blockIdx.y * 256;  // column chunk base in W2

    // A-recompute: 2 m-rows x 4 k per thread (64 row-pairs x 8 k-groups)
    int mg = tid >> 3;   // 0..63 -> rows 2mg, 2mg+1
    int kg = tid & 7;    // k group: kg*4 .. kg*4+3
    float a0[2], a1[2], a2[2];
#pragma unroll
    for (int j = 0; j < 2; ++j) {
        int gm = m0 + mg * 2 + j;
        if (gm < NN) {
            a0[j] = aggx[gm * 3 + 0];
            a1[j] = aggx[gm * 3 + 1];
            a2[j] = aggx[gm * 3 + 2];
        } else {
            a0[j] = a1[j] = a2[j] = 0.f;
        }
    }

    // B staging: 2 threads per n-row, 16 f16 each
    int brow = tid >> 1;            // 0..255
    int bkof = (tid & 1) * 16;
    const f16* bbase = Bt + (size_t)(n0c + brow) * 4096 + bkof;

    int lane   = tid & 63;
    int wv     = tid >> 6;          // 0..7
    int wm     = (wv >> 2) * 64;    // 0 or 64
    int wn     = (wv & 3) * 64;     // 0,64,128,192
    int fr_m   = lane & 15;
    int khalf8 = (lane >> 4) * 8;

    // Prefetch B for k0 = 0
    h8 pb0 = *(const h8*)(bbase);
    h8 pb1 = *(const h8*)(bbase + 8);

    f32x4 acc[4][4];
#pragma unroll
    for (int i = 0; i < 4; ++i)
#pragma unroll
        for (int j = 0; j < 4; ++j) acc[i][j] = (f32x4){0.f, 0.f, 0.f, 0.f};

    for (int k0 = 0; k0 < 4096; k0 += 32) {
        // ---- A-tile: h1 (f16) for 2 m x 4 k; w1p read at use (L1-hot) ----
        int kb = k0 + kg * 4;
        float4 wk0 = *(const float4*)(w1p + (size_t)(kb + 0) * 4);
        float4 wk1 = *(const float4*)(w1p + (size_t)(kb + 1) * 4);
        float4 wk2 = *(const float4*)(w1p + (size_t)(kb + 2) * 4);
        float4 wk3 = *(const float4*)(w1p + (size_t)(kb + 3) * 4);
#pragma unroll
        for (int j = 0; j < 2; ++j) {
            float h0 = fmaxf(a0[j] * wk0.x + a1[j] * wk0.y + a2[j] * wk0.z + wk0.w, 0.f);
            float h1 = fmaxf(a0[j] * wk1.x + a1[j] * wk1.y + a2[j] * wk1.z + wk1.w, 0.f);
            float h2 = fmaxf(a0[j] * wk2.x + a1[j] * wk2.y + a2[j] * wk2.z + wk2.w, 0.f);
            float h3 = fmaxf(a0[j] * wk3.x + a1[j] * wk3.y + a2[j] * wk3.z + wk3.w, 0.f);
            Pack4 pk;
            pk.h[0] = (f16)h0; pk.h[1] = (f16)h1; pk.h[2] = (f16)h2; pk.h[3] = (f16)h3;
            *(uint2*)(&As[(mg * 2 + j) * LDSTR + kg * 4]) = pk.v;
        }
        // ---- B-tile from prefetched regs ----
        *(h8*)(&Bs[brow * LDSTR + bkof]) = pb0;
        *(h8*)(&Bs[brow * LDSTR + bkof + 8]) = pb1;
        __syncthreads();

        // ---- Prefetch next B slice (drains under MFMA phase) ----
        int kn = k0 + 32;
        if (kn < 4096) {
            pb0 = *(const h8*)(bbase + kn);
            pb1 = *(const h8*)(bbase + kn + 8);
        }

        h8 af[4];
#pragma unroll
        for (int mt = 0; mt < 4; ++mt)
            af[mt] = *(const h8*)(&As[(wm + mt * 16 + fr_m) * LDSTR + khalf8]);
#pragma unroll
        for (int nt = 0; nt < 4; ++nt) {
            h8 bf = *(const h8*)(&Bs[(wn + nt * 16 + fr_m) * LDSTR + khalf8]);
#pragma unroll
            for (int mt = 0; mt < 4; ++mt)
                acc[mt][nt] = __builtin_amdgcn_mfma_f32_16x16x32_f16(af[mt], bf, acc[mt][nt], 0, 0, 0);
        }
        __syncthreads();
    }

#pragma unroll
    for (int mt = 0; mt < 4; ++mt) {
#pragma unroll
        for (int reg = 0; reg < 4; ++reg) {
            int gm = m0 + wm + mt * 16 + (lane >> 4) * 4 + reg;
            if (gm < NN) {
                unsigned char* orow = t2 + (size_t)gm * 1024 + n0c + wn + fr_m;
#pragma unroll
                for (int nt = 0; nt < 4; ++nt)
                    orow[nt * 16] = f2fp8(acc[mt][nt][reg]);
            }
        }
    }
}

// Generic MFMA GEMM (layer 3): C(fp8)[M,ldc] = A[M,lda](f16) @ Bt[N][K](f16)^T
// 128x128 tile, register-prefetched staging. 20.5 KB LDS -> 8 blocks/CU.
__global__ __launch_bounds__(256) void gemm_mfma(const f16* __restrict__ A, int lda,
                                                 const f16* __restrict__ Bt, int K,
                                                 unsigned char* __restrict__ C, int ldc,
                                                 int M) {
    __shared__ f16 As[128 * LDSTR] __attribute__((aligned(16)));
    __shared__ f16 Bs[128 * LDSTR] __attribute__((aligned(16)));
    int tid = threadIdx.x;
    int m0 = blockIdx.y * 128;
    int n0 = blockIdx.x * 128;

    int row = tid >> 1;
    int kof = (tid & 1) * 16;
    int am  = m0 + row;
    if (am > M - 1) am = M - 1;

    int lane   = tid & 63;
    int wv     = tid >> 6;
    int fr_m   = lane & 15;
    int khalf8 = (lane >> 4) * 8;

    const f16* abase = A + (size_t)am * lda + kof;
    const f16* bbase = Bt + (size_t)(n0 + row) * K + kof;

    h8 pa0 = *(const h8*)(abase);
    h8 pa1 = *(const h8*)(abase + 8);
    h8 pb0 = *(const h8*)(bbase);
    h8 pb1 = *(const h8*)(bbase + 8);

    f32x4 acc[2][8];
#pragma unroll
    for (int i = 0; i < 2; ++i)
#pragma unroll
        for (int j = 0; j < 8; ++j) acc[i][j] = (f32x4){0.f, 0.f, 0.f, 0.f};

    for (int k0 = 0; k0 < K; k0 += 32) {
        *(h8*)(&As[row * LDSTR + kof]) = pa0;
        *(h8*)(&As[row * LDSTR + kof + 8]) = pa1;
        *(h8*)(&Bs[row * LDSTR + kof]) = pb0;
        *(h8*)(&Bs[row * LDSTR + kof + 8]) = pb1;
        __syncthreads();

        int kn = k0 + 32;
        if (kn < K) {
            pa0 = *(const h8*)(abase + kn);
            pa1 = *(const h8*)(abase + kn + 8);
            pb0 = *(const h8*)(bbase + kn);
            pb1 = *(const h8*)(bbase + kn + 8);
        }

        h8 af0 = *(const h8*)(&As[(wv * 32 + fr_m) * LDSTR + khalf8]);
        h8 af1 = *(const h8*)(&As[(wv * 32 + 16 + fr_m) * LDSTR + khalf8]);
#pragma unroll
        for (int nt = 0; nt < 8; ++nt) {
            h8 bf = *(const h8*)(&Bs[(nt * 16 + fr_m) * LDSTR + khalf8]);
            acc[0][nt] = __builtin_amdgcn_mfma_f32_16x16x32_f16(af0, bf, acc[0][nt], 0, 0, 0);
            acc[1][nt] = __builtin_amdgcn_mfma_f32_16x16x32_f16(af1, bf, acc[1][nt], 0, 0, 0);
        }
        __syncthreads();
    }

#pragma unroll
    for (int mt = 0; mt < 2; ++mt) {
#pragma unroll
        for (int reg = 0; reg < 4; ++reg) {
            int gm = m0 + wv * 32 + mt * 16 + (lane >> 4) * 4 + reg;
            if (gm < M) {
                unsigned char* orow = C + (size_t)gm * ldc + n0 + fr_m;
#pragma unroll
                for (int nt = 0; nt < 8; ++nt)
                    orow[nt * 16] = f2fp8(acc[mt][nt][reg]);
            }
        }
    }
}

// ---------------------------------------------------------------------------
// Layer-4 GEMM: C[M,64] f32 = A[M,256](f16) @ B[256,64](f32)
// ---------------------------------------------------------------------------
#define BM 64
#define BN 64
#define BKS 16
__global__ __launch_bounds__(256) void gemm_f16A_kernel(const f16* __restrict__ A,
                                                        const float* __restrict__ B,
                                                        float* __restrict__ C,
                                                        int M, int K, int N) {
    __shared__ float As[BKS][BM + 4];
    __shared__ float Bs[BKS][BN + 4];
    int tid = threadIdx.x;
    int tx = tid & 15;
    int ty = tid >> 4;
    int m0 = blockIdx.y * BM;
    int n0 = blockIdx.x * BN;

    float acc[4][4];
#pragma unroll
    for (int i = 0; i < 4; ++i)
#pragma unroll
        for (int j = 0; j < 4; ++j) acc[i][j] = 0.f;

    int lmA = tid >> 2;
    int lkA = (tid & 3) * 4;
    int lkB = tid >> 4;
    int lnB = (tid & 15) * 4;

    for (int k0 = 0; k0 < K; k0 += BKS) {
        int gm = m0 + lmA;
        if (gm > M - 1) gm = M - 1;
        h4v av = *(const h4v*)(A + (size_t)gm * K + k0 + lkA);
        As[lkA + 0][lmA] = (float)av.x;
        As[lkA + 1][lmA] = (float)av.y;
        As[lkA + 2][lmA] = (float)av.z;
        As[lkA + 3][lmA] = (float)av.w;
        float4 bv = *reinterpret_cast<const float4*>(B + (size_t)(k0 + lkB) * N + n0 + lnB);
        *reinterpret_cast<float4*>(&Bs[lkB][lnB]) = bv;
        __syncthreads();

#pragma unroll
        for (int k = 0; k < BKS; ++k) {
            float4 a4 = *reinterpret_cast<const float4*>(&As[k][ty * 4]);
            float4 b4 = *reinterpret_cast<const float4*>(&Bs[k][tx * 4]);
            float a[4] = {a4.x, a4.y, a4.z, a4.w};
            float b[4] = {b4.x, b4.y, b4.z, b4.w};
#pragma unroll
            for (int i = 0; i < 4; ++i)
#pragma unroll
                for (int j = 0; j < 4; ++j) acc[i][j] += a[i] * b[j];
        }
        __syncthreads();
    }

#pragma unroll
    for (int i = 0; i < 4; ++i) {
        int m = m0 + ty * 4 + i;
        if (m < M) {
            float4 o = make_float4(acc[i][0], acc[i][1], acc[i][2], acc[i][3]);
            *reinterpret_cast<float4*>(C + (size_t)m * N + n0 + tx * 4) = o;
        }
    }
}

// Layer-5 GEMM: t5 = h4[NN,64](f16) @ W5[64,16](f32)
__global__ __launch_bounds__(256) void gemm5_kernel(const f16* __restrict__ h4,
                                                    const float* __restrict__ W5,
                                                    float* __restrict__ t5, int nNodes) {
    int idx = blockIdx.x * 256 + threadIdx.x;
    int i = idx >> 4, j = idx & 15;
    if (i >= nNodes) return;
    const f16* a = h4 + (size_t)i * 64;
    float s = 0.f;
#pragma unroll
    for (int k = 0; k < 64; ++k) s += (float)a[k] * W5[k * 16 + j];
    t5[idx] = s;
}

// Pool + classifier
__global__ __launch_bounds__(256) void pool_kernel(const float* __restrict__ h5,
                                                   float* __restrict__ pool) {
    __shared__ float red[256];
    int c = blockIdx.x;
    float s = 0.f;
    for (int i = threadIdx.x; i < NN; i += 256) s += h5[(size_t)i * 16 + c];
    red[threadIdx.x] = s;
    __syncthreads();
    for (int off = 128; off > 0; off >>= 1) {
        if ((int)threadIdx.x < off) red[threadIdx.x] += red[threadIdx.x + off];
        __syncthreads();
    }
    if (threadIdx.x == 0) pool[c] = red[0];
}

__global__ void final_kernel(const float* __restrict__ pool, const float* __restrict__ Wl,
                             const float* __restrict__ bl, float* __restrict__ out) {
    int j = threadIdx.x;
    if (j < 3) {
        float s = 0.f;
#pragma unroll
        for (int c = 0; c < 16; ++c) s += pool[c] * Wl[c * 3 + j];
        out[j] = s * (1.0f / (float)NN) + bl[j];
    }
}

// ---------------------------------------------------------------------------
// Host launcher — workspace ledger identical to rounds 7-12 (~205 MB, proven).
// ---------------------------------------------------------------------------
extern "C" void kernel_launch(void* const* d_in, const int* in_sizes, int n_in,
                              void* d_out, int out_size, void* d_ws, size_t ws_size,
                              hipStream_t stream) {
    (void)in_sizes; (void)n_in; (void)out_size; (void)ws_size;

    const float* x  = (const float*)d_in[0];
    const int*   ei = (const int*)d_in[1];
    const float* W1 = (const float*)d_in[2];
    const float* b1 = (const float*)d_in[3];
    const float* W2 = (const float*)d_in[4];
    const float* b2 = (const float*)d_in[5];
    const float* W3 = (const float*)d_in[6];
    const float* b3 = (const float*)d_in[7];
    const float* W4 = (const float*)d_in[8];
    const float* b4 = (const float*)d_in[9];
    const float* W5 = (const float*)d_in[10];
    const float* b5 = (const float*)d_in[11];
    const float* Wl = (const float*)d_in[12];
    const float* bl = (const float*)d_in[13];
    float* out = (float*)d_out;

    const int* srcp = ei;
    const int* dstp = ei + NE;

    char* p = (char*)d_ws;
    auto carve = [&](size_t bytes) {
        char* r = p;
        p += (bytes + 255) & ~(size_t)255;
        return r;
    };
    int*   deg  = (int*)carve(NN * 4);
    int*   cur  = (int*)carve(NN * 4);
    int*   rs   = (int*)carve((NN + 1) * 4);
    int*   bsum = (int*)carve(256 * 4);
    int*   csr  = (int*)carve((size_t)NE * 4);
    float* dinv = (float*)carve(NN * 4);
    float* aggx = (float*)carve((size_t)NN * 3 * 4);
    float* pool = (float*)carve(16 * 4);
    float* w1p  = (float*)carve((size_t)4096 * 4 * 4);       // 64 KB
    f16*   w2t  = (f16*)carve((size_t)1024 * 4096 * 2);      // 8.4 MB
    f16*   w3t  = (f16*)carve((size_t)256 * 1024 * 2);       // 0.5 MB
    unsigned char* tbuf = (unsigned char*)carve((size_t)NN * 1024);  // 51.2 MB: fp8 t2[NN,1024] / t3 / f32 t4,t5 view
    f16*   h2   = (f16*)carve((size_t)NN * 1024 * 2);        // 102.4 MB
    f16*   h3   = (f16*)carve((size_t)NN * 256 * 2);         // 25.6 MB
    f16*   h4   = (f16*)carve((size_t)NN * 64 * 2);          // 6.4 MB
    float* h5   = (float*)carve((size_t)NN * 16 * 4);        // 3.2 MB
    float* tf32 = (float*)tbuf;                              // f32 view for t4/t5

    const int NB = (NN + 255) / 256;  // 196

    zero_int_kernel<<<NB, 256, 0, stream>>>(deg, NN);
    zero_int_kernel<<<NB, 256, 0, stream>>>(cur, NN);
    count_kernel<<<(NE + 255) / 256, 256, 0, stream>>>(dstp, deg, NE);
    dinv_kernel<<<NB, 256, 0, stream>>>(deg, dinv, NN);
    scan1_kernel<<<NB, 256, 0, stream>>>(deg, rs, bsum, NN);
    scan2_kernel<<<1, 256, 0, stream>>>(bsum, rs, NB, NN);
    scan3_kernel<<<NB, 256, 0, stream>>>(rs, bsum, NN);
    fill_kernel<<<(NE + 255) / 256, 256, 0, stream>>>(srcp, dstp, rs, cur, csr, NE);

    // Weight prep
    pack_w1_kernel<<<16, 256, 0, stream>>>(W1, b1, w1p);
    tconv_kernel<<<dim3(1024 / 32, 4096 / 32), 256, 0, stream>>>(W2, w2t, 4096, 1024);
    tconv_kernel<<<dim3(256 / 32, 1024 / 32), 256, 0, stream>>>(W3, w3t, 1024, 256);

    // aggx = A_hat @ x (width 3, fp32)
    agg_kernel<3, 1, false, false, float><<<NB, 256, 0, stream>>>(
        x, dinv, rs, csr, nullptr, aggx, 3, NN);

    const int MB2 = (NN + 127) / 128;  // 391
    const int AB  = (NN + 15) / 16;    // 3125 blocks for agg_fp8_64

    // Layers 1+2 fused: one 512-thread MFMA launch for all 1024 cols (fp8 out)
    gemm12_mfma4<<<dim3(MB2, 4), 512, 0, stream>>>(aggx, w1p, w2t, tbuf);
    // h2 = relu(A_hat t2 + b2): 16 column-slice passes (3.2 MB L2-resident each)
    for (int c = 0; c < 16; ++c) {
        int c0 = c * 64;
        agg_fp8_64<true><<<AB, 256, 0, stream>>>(
            tbuf + c0, 1024, dinv, rs, csr, b2 + c0, h2 + c0, 1024, NN);
    }

    // Layer 3 (MFMA, fp8 out): t3 = h2 @ W3; h3 = relu(A_hat t3 + b3)
    gemm_mfma<<<dim3(2, MB2), 256, 0, stream>>>(
        h2, 1024, w3t, 1024, tbuf, 256, NN);
    for (int c = 0; c < 4; ++c) {
        int c0 = c * 64;
        agg_fp8_64<true><<<AB, 256, 0, stream>>>(
            tbuf + c0, 256, dinv, rs, csr, b3 + c0, h3 + c0, 256, NN);
    }

    // Layer 4: t4 = h3 @ W4 [NN,64] f32; h4 = relu(A_hat t4 + b4) -> f16
    gemm_f16A_kernel<<<dim3(1, (NN + BM - 1) / BM), 256, 0, stream>>>(
        h3, W4, tf32, NN, 256, 64);
    agg_kernel<64, 64, true, true, f16><<<(NN + 3) / 4, 256, 0, stream>>>(
        tf32, dinv, rs, csr, b4, h4, 64, NN);

    // Layer 5: t5 = h4 @ W5 [NN,16] f32; h5 = A_hat t5 + b5 (no relu)
    gemm5_kernel<<<(NN * 16 + 255) / 256, 256, 0, stream>>>(h4, W5, tf32, NN);
    agg_kernel<16, 16, false, true, float><<<(NN + 15) / 16, 256, 0, stream>>>(
        tf32, dinv, rs, csr, b5, h5, 16, NN);

    // Global mean pool + classifier
    pool_kernel<<<16, 256, 0, stream>>>(h5, pool);
    final_kernel<<<1, 64, 0, stream>>>(pool, Wl, bl, out);
}

// Round 14
// 1635.114 us; speedup vs baseline: 1.4271x; 1.4271x over previous
//
#include <hip/hip_runtime.h>
#include <stdint.h>

#define NN 50000
#define NE 1600000

typedef _Float16 f16;
typedef __attribute__((ext_vector_type(8))) _Float16 h8;
typedef __attribute__((ext_vector_type(4))) _Float16 h4v;
typedef __attribute__((ext_vector_type(4))) float f32x4;
typedef __attribute__((ext_vector_type(2))) float f32x2;

union PackU { unsigned int u; f16 h[2]; };
union Pack4 { uint2 v; f16 h[4]; };
union Pack8 { uint4 v; f16 h[8]; };

__device__ __forceinline__ void storev(float* p, float v) { *p = v; }
__device__ __forceinline__ void storev(f16* p, float v) { *p = (f16)v; }

__device__ __forceinline__ unsigned char f2fp8(float v) {
    int pk = __builtin_amdgcn_cvt_pk_fp8_f32(v, v, 0, false);
    return (unsigned char)(pk & 0xff);
}

// ---------------------------------------------------------------------------
// Preprocessing
// ---------------------------------------------------------------------------
__global__ __launch_bounds__(256) void zero_int_kernel(int* __restrict__ p, int n) {
    int i = blockIdx.x * 256 + threadIdx.x;
    if (i < n) p[i] = 0;
}

__global__ __launch_bounds__(256) void count_kernel(const int* __restrict__ dst,
                                                    int* __restrict__ deg, int nE) {
    int e = blockIdx.x * 256 + threadIdx.x;
    if (e < nE) atomicAdd(&deg[dst[e]], 1);
}

__global__ __launch_bounds__(256) void dinv_kernel(const int* __restrict__ deg,
                                                   float* __restrict__ dinv, int n) {
    int i = blockIdx.x * 256 + threadIdx.x;
    if (i < n) dinv[i] = rsqrtf((float)deg[i] + 1.0f);
}

// Parallel 3-phase exclusive scan over 50000 ints (196 blocks of 256).
__global__ __launch_bounds__(256) void scan1_kernel(const int* __restrict__ cnt,
                                                    int* __restrict__ rs,
                                                    int* __restrict__ bsum, int n) {
    __shared__ int sm[256];
    int b = blockIdx.x, t = threadIdx.x, i = b * 256 + t;
    int v = (i < n) ? cnt[i] : 0;
    sm[t] = v;
    __syncthreads();
    for (int off = 1; off < 256; off <<= 1) {
        int x = 0;
        if (t >= off) x = sm[t - off];
        __syncthreads();
        if (t >= off) sm[t] += x;
        __syncthreads();
    }
    if (i < n) rs[i] = sm[t] - v;  // block-local exclusive
    if (t == 255) bsum[b] = sm[255];
}

__global__ __launch_bounds__(256) void scan2_kernel(int* __restrict__ bsum,
                                                    int* __restrict__ rs, int nb, int n) {
    __shared__ int sm[256];
    int t = threadIdx.x;
    int v = (t < nb) ? bsum[t] : 0;
    sm[t] = v;
    __syncthreads();
    for (int off = 1; off < 256; off <<= 1) {
        int x = 0;
        if (t >= off) x = sm[t - off];
        __syncthreads();
        if (t >= off) sm[t] += x;
        __syncthreads();
    }
    if (t < nb) bsum[t] = sm[t] - v;  // exclusive block offsets
    if (t == 255) rs[n] = sm[255];    // grand total (= nE)
}

__global__ __launch_bounds__(256) void scan3_kernel(int* __restrict__ rs,
                                                    const int* __restrict__ bsum, int n) {
    int i = blockIdx.x * 256 + threadIdx.x;
    if (i < n) rs[i] += bsum[blockIdx.x];
}

__global__ __launch_bounds__(256) void fill_kernel(const int* __restrict__ src,
                                                   const int* __restrict__ dst,
                                                   const int* __restrict__ rs,
                                                   int* __restrict__ cur,
                                                   int* __restrict__ csr, int nE) {
    int e = blockIdx.x * 256 + threadIdx.x;
    if (e < nE) {
        int d = dst[e];
        int p = rs[d] + atomicAdd(&cur[d], 1);
        csr[p] = src[e];
    }
}

// w1p[k*4 + {0,1,2,3}] = {W1[0][k], W1[1][k], W1[2][k], b1[k]}
__global__ __launch_bounds__(256) void pack_w1_kernel(const float* __restrict__ W1,
                                                      const float* __restrict__ b1,
                                                      float* __restrict__ w1p) {
    int k = blockIdx.x * 256 + threadIdx.x;
    if (k < 4096) {
        w1p[k * 4 + 0] = W1[k];
        w1p[k * 4 + 1] = W1[4096 + k];
        w1p[k * 4 + 2] = W1[8192 + k];
        w1p[k * 4 + 3] = b1[k];
    }
}

// Transpose-convert: Wt[n][k] = f16(W[k][n]); K, N multiples of 32.
__global__ __launch_bounds__(256) void tconv_kernel(const float* __restrict__ W,
                                                    f16* __restrict__ Wt,
                                                    int K, int N) {
    __shared__ float tile[32][33];
    int kb = blockIdx.y * 32, nb = blockIdx.x * 32;
    int tx = threadIdx.x & 31, ty = threadIdx.x >> 5;
    for (int r = ty; r < 32; r += 8)
        tile[r][tx] = W[(size_t)(kb + r) * N + nb + tx];
    __syncthreads();
    for (int r = ty; r < 32; r += 8)
        Wt[(size_t)(nb + r) * K + kb + tx] = (f16)tile[tx][r];
}

// ---------------------------------------------------------------------------
// fp32-input aggregation (widths 3, 64, 16)
// ---------------------------------------------------------------------------
template <int F, int TPN, bool RELU, bool BIAS, typename OutT>
__global__ __launch_bounds__(256) void agg_kernel(const float* __restrict__ t,
                                                  const float* __restrict__ dinv,
                                                  const int* __restrict__ rs,
                                                  const int* __restrict__ csr,
                                                  const float* __restrict__ bias,
                                                  OutT* __restrict__ out, int out_ld,
                                                  int nNodes) {
    constexpr int NPB = 256 / TPN;
    constexpr int C   = F / TPN;
    static_assert(TPN * C == F, "F must be TPN*C");
    int node = blockIdx.x * NPB + (int)threadIdx.x / TPN;
    if (node >= nNodes) return;
    int lane = (int)threadIdx.x % TPN;

    float acc[C];
#pragma unroll
    for (int c = 0; c < C; ++c) acc[c] = 0.f;

    int e0 = rs[node], e1 = rs[node + 1];
    for (int e = e0; e < e1; ++e) {
        int s = csr[e];
        float w = dinv[s];
        const float* tr = t + (size_t)s * F;
#pragma unroll
        for (int c = 0; c < C; ++c) acc[c] += w * tr[lane + c * TPN];
    }
    float di = dinv[node];
    const float* ti = t + (size_t)node * F;
    OutT* oi = out + (size_t)node * out_ld;
#pragma unroll
    for (int c = 0; c < C; ++c) {
        int col = lane + c * TPN;
        float v = di * acc[c] + di * di * ti[col];
        if (BIAS) v += bias[col];
        if (RELU) v = fmaxf(v, 0.f);
        storev(oi + col, v);
    }
}

// ---------------------------------------------------------------------------
// fp8 aggregation, F=1024, SINGLE PASS: 64 lanes/node (4 nodes/block), each
// lane loads a uint4 (16 B = 16 fp8 cols) per edge -> one VMEM instruction
// covers the whole 1 KB row per wave. Keeps 64-lane/node parallelism (round-13
// regression was from cutting lanes 64->16) while reading csr/dinv once
// instead of 4x and launching once instead of 4x.
// ---------------------------------------------------------------------------
template <bool RELU>
__global__ __launch_bounds__(256) void agg_fp8_1024(const unsigned char* __restrict__ t,
                                                    const float* __restrict__ dinv,
                                                    const int* __restrict__ rs,
                                                    const int* __restrict__ csr,
                                                    const float* __restrict__ bias,
                                                    f16* __restrict__ out, int nNodes) {
    int node = blockIdx.x * 4 + ((int)threadIdx.x >> 6);
    if (node >= nNodes) return;
    int lane = (int)threadIdx.x & 63;

    float acc[16];
#pragma unroll
    for (int j = 0; j < 16; ++j) acc[j] = 0.f;

    int e0 = rs[node], e1 = rs[node + 1];
    int e = e0;
    for (; e + 1 < e1; e += 2) {
        int s0 = csr[e], s1 = csr[e + 1];
        float w0 = dinv[s0], w1 = dinv[s1];
        uint4 u0 = ((const uint4*)(t + (size_t)s0 * 1024))[lane];
        uint4 u1 = ((const uint4*)(t + (size_t)s1 * 1024))[lane];
        const unsigned int uw0[4] = {u0.x, u0.y, u0.z, u0.w};
        const unsigned int uw1[4] = {u1.x, u1.y, u1.z, u1.w};
#pragma unroll
        for (int q = 0; q < 4; ++q) {
            f32x2 l0 = __builtin_amdgcn_cvt_pk_f32_fp8((int)uw0[q], false);
            f32x2 h0 = __builtin_amdgcn_cvt_pk_f32_fp8((int)uw0[q], true);
            f32x2 l1 = __builtin_amdgcn_cvt_pk_f32_fp8((int)uw1[q], false);
            f32x2 h1 = __builtin_amdgcn_cvt_pk_f32_fp8((int)uw1[q], true);
            acc[q * 4 + 0] += w0 * l0.x + w1 * l1.x;
            acc[q * 4 + 1] += w0 * l0.y + w1 * l1.y;
            acc[q * 4 + 2] += w0 * h0.x + w1 * h1.x;
            acc[q * 4 + 3] += w0 * h0.y + w1 * h1.y;
        }
    }
    if (e < e1) {
        int s0 = csr[e];
        float w0 = dinv[s0];
        uint4 u0 = ((const uint4*)(t + (size_t)s0 * 1024))[lane];
        const unsigned int uw0[4] = {u0.x, u0.y, u0.z, u0.w};
#pragma unroll
        for (int q = 0; q < 4; ++q) {
            f32x2 l0 = __builtin_amdgcn_cvt_pk_f32_fp8((int)uw0[q], false);
            f32x2 h0 = __builtin_amdgcn_cvt_pk_f32_fp8((int)uw0[q], true);
            acc[q * 4 + 0] += w0 * l0.x;
            acc[q * 4 + 1] += w0 * l0.y;
            acc[q * 4 + 2] += w0 * h0.x;
            acc[q * 4 + 3] += w0 * h0.y;
        }
    }
    float di = dinv[node], di2 = di * di;
    uint4 us = ((const uint4*)(t + (size_t)node * 1024))[lane];
    const unsigned int uws[4] = {us.x, us.y, us.z, us.w};
    Pack8 o0, o1;
#pragma unroll
    for (int q = 0; q < 4; ++q) {
        f32x2 sl = __builtin_amdgcn_cvt_pk_f32_fp8((int)uws[q], false);
        f32x2 sh = __builtin_amdgcn_cvt_pk_f32_fp8((int)uws[q], true);
        float4 b = *(const float4*)(bias + 16 * lane + q * 4);
        float v0 = di * acc[q * 4 + 0] + di2 * sl.x + b.x;
        float v1 = di * acc[q * 4 + 1] + di2 * sl.y + b.y;
        float v2 = di * acc[q * 4 + 2] + di2 * sh.x + b.z;
        float v3 = di * acc[q * 4 + 3] + di2 * sh.y + b.w;
        if (RELU) {
            v0 = fmaxf(v0, 0.f); v1 = fmaxf(v1, 0.f);
            v2 = fmaxf(v2, 0.f); v3 = fmaxf(v3, 0.f);
        }
        Pack8& dst8 = (q < 2) ? o0 : o1;
        int base = (q & 1) * 4;
        dst8.h[base + 0] = (f16)v0;
        dst8.h[base + 1] = (f16)v1;
        dst8.h[base + 2] = (f16)v2;
        dst8.h[base + 3] = (f16)v3;
    }
    uint4* orow = (uint4*)(out + (size_t)node * 1024 + 16 * lane);
    orow[0] = o0.v;
    orow[1] = o1.v;
}

// ---------------------------------------------------------------------------
// fp8 aggregation over a 256-col tensor (layer 3): 64 lanes/node, one uint
// (4 fp8 cols) per lane per edge. Round-8-proven structure.
// ---------------------------------------------------------------------------
template <bool RELU>
__global__ __launch_bounds__(256) void agg_fp8_256(const unsigned char* __restrict__ t,
                                                   int in_ld,
                                                   const float* __restrict__ dinv,
                                                   const int* __restrict__ rs,
                                                   const int* __restrict__ csr,
                                                   const float* __restrict__ bias,
                                                   f16* __restrict__ out,
                                                   int out_ld, int nNodes) {
    int node = blockIdx.x * 4 + ((int)threadIdx.x >> 6);
    if (node >= nNodes) return;
    int lane = (int)threadIdx.x & 63;

    float acc0 = 0.f, acc1 = 0.f, acc2 = 0.f, acc3 = 0.f;
    int e0 = rs[node], e1 = rs[node + 1];
    int e = e0;
    for (; e + 1 < e1; e += 2) {
        int s0 = csr[e], s1 = csr[e + 1];
        float w0 = dinv[s0], w1 = dinv[s1];
        unsigned int u0 = ((const unsigned int*)(t + (size_t)s0 * in_ld))[lane];
        unsigned int u1 = ((const unsigned int*)(t + (size_t)s1 * in_ld))[lane];
        f32x2 l0 = __builtin_amdgcn_cvt_pk_f32_fp8((int)u0, false);
        f32x2 h0 = __builtin_amdgcn_cvt_pk_f32_fp8((int)u0, true);
        f32x2 l1 = __builtin_amdgcn_cvt_pk_f32_fp8((int)u1, false);
        f32x2 h1 = __builtin_amdgcn_cvt_pk_f32_fp8((int)u1, true);
        acc0 += w0 * l0.x + w1 * l1.x;
        acc1 += w0 * l0.y + w1 * l1.y;
        acc2 += w0 * h0.x + w1 * h1.x;
        acc3 += w0 * h0.y + w1 * h1.y;
    }
    if (e < e1) {
        int s0 = csr[e];
        float w0 = dinv[s0];
        unsigned int u0 = ((const unsigned int*)(t + (size_t)s0 * in_ld))[lane];
        f32x2 l0 = __builtin_amdgcn_cvt_pk_f32_fp8((int)u0, false);
        f32x2 h0 = __builtin_amdgcn_cvt_pk_f32_fp8((int)u0, true);
        acc0 += w0 * l0.x;
        acc1 += w0 * l0.y;
        acc2 += w0 * h0.x;
        acc3 += w0 * h0.y;
    }
    float di = dinv[node], di2 = di * di;
    unsigned int us = ((const unsigned int*)(t + (size_t)node * in_ld))[lane];
    f32x2 sl = __builtin_amdgcn_cvt_pk_f32_fp8((int)us, false);
    f32x2 sh = __builtin_amdgcn_cvt_pk_f32_fp8((int)us, true);
    float4 b = *(const float4*)(bias + 4 * lane);
    float v0 = di * acc0 + di2 * sl.x + b.x;
    float v1 = di * acc1 + di2 * sl.y + b.y;
    float v2 = di * acc2 + di2 * sh.x + b.z;
    float v3 = di * acc3 + di2 * sh.y + b.w;
    if (RELU) {
        v0 = fmaxf(v0, 0.f); v1 = fmaxf(v1, 0.f);
        v2 = fmaxf(v2, 0.f); v3 = fmaxf(v3, 0.f);
    }
    Pack4 pk;
    pk.h[0] = (f16)v0; pk.h[1] = (f16)v1; pk.h[2] = (f16)v2; pk.h[3] = (f16)v3;
    *(uint2*)(out + (size_t)node * out_ld + 4 * lane) = pk.v;
}

// ---------------------------------------------------------------------------
// MFMA GEMM kernels. LDS row stride 40 f16 = 80 B (16 B-aligned).
// Fragments: A[m=lane&15][k=(lane>>4)*8+j]; B^T rows; C/D col=lane&15,
// row=(lane>>4)*4+reg.
// ---------------------------------------------------------------------------
#define LDSTR 40

// Fused layer1+2 (round-11 structure — best measured at 752 us).
// 512 threads = 8 waves (2m x 4n, each 64m x 64n, 16 MFMA/K-step).
// 128m x 256n tile. A-tile (h1 = relu(aggx@W1+b1) f16) computed on the fly.
// Output fp8 into t2[NN][1024].
__global__ __launch_bounds__(512, 4) void gemm12_mfma4(const float* __restrict__ aggx,
                                                       const float* __restrict__ w1p,
                                                       const f16* __restrict__ Bt,
                                                       unsigned char* __restrict__ t2) {
    __shared__ f16 As[128 * LDSTR] __attribute__((aligned(16)));
    __shared__ f16 Bs[256 * LDSTR] __attribute__((aligned(16)));
    int tid = threadIdx.x;
    int m0  = blockIdx.x * 128;
    int n0c = blockIdx.y * 256;  // column chunk base in W2

    // A-recompute: 2 m-rows x 4 k per thread (64 row-pairs x 8 k-groups)
    int mg = tid >> 3;   // 0..63 -> rows 2mg, 2mg+1
    int kg = tid & 7;    // k group: kg*4 .. kg*4+3
    float a0[2], a1[2], a2[2];
#pragma unroll
    for (int j = 0; j < 2; ++j) {
        int gm = m0 + mg * 2 + j;
        if (gm < NN) {
            a0[j] = aggx[gm * 3 + 0];
            a1[j] = aggx[gm * 3 + 1];
            a2[j] = aggx[gm * 3 + 2];
        } else {
            a0[j] = a1[j] = a2[j] = 0.f;
        }
    }

    // B staging: 2 threads per n-row, 16 f16 each
    int brow = tid >> 1;            // 0..255
    int bkof = (tid & 1) * 16;
    const f16* bbase = Bt + (size_t)(n0c + brow) * 4096 + bkof;

    int lane   = tid & 63;
    int wv     = tid >> 6;          // 0..7
    int wm     = (wv >> 2) * 64;    // 0 or 64
    int wn     = (wv & 3) * 64;     // 0,64,128,192
    int fr_m   = lane & 15;
    int khalf8 = (lane >> 4) * 8;

    // Prefetch B for k0 = 0
    h8 pb0 = *(const h8*)(bbase);
    h8 pb1 = *(const h8*)(bbase + 8);

    f32x4 acc[4][4];
#pragma unroll
    for (int i = 0; i < 4; ++i)
#pragma unroll
        for (int j = 0; j < 4; ++j) acc[i][j] = (f32x4){0.f, 0.f, 0.f, 0.f};

    for (int k0 = 0; k0 < 4096; k0 += 32) {
        // ---- A-tile: h1 (f16) for 2 m x 4 k; w1p read at use (L1-hot) ----
        int kb = k0 + kg * 4;
        float4 wk0 = *(const float4*)(w1p + (size_t)(kb + 0) * 4);
        float4 wk1 = *(const float4*)(w1p + (size_t)(kb + 1) * 4);
        float4 wk2 = *(const float4*)(w1p + (size_t)(kb + 2) * 4);
        float4 wk3 = *(const float4*)(w1p + (size_t)(kb + 3) * 4);
#pragma unroll
        for (int j = 0; j < 2; ++j) {
            float h0 = fmaxf(a0[j] * wk0.x + a1[j] * wk0.y + a2[j] * wk0.z + wk0.w, 0.f);
            float h1 = fmaxf(a0[j] * wk1.x + a1[j] * wk1.y + a2[j] * wk1.z + wk1.w, 0.f);
            float h2 = fmaxf(a0[j] * wk2.x + a1[j] * wk2.y + a2[j] * wk2.z + wk2.w, 0.f);
            float h3 = fmaxf(a0[j] * wk3.x + a1[j] * wk3.y + a2[j] * wk3.z + wk3.w, 0.f);
            Pack4 pk;
            pk.h[0] = (f16)h0; pk.h[1] = (f16)h1; pk.h[2] = (f16)h2; pk.h[3] = (f16)h3;
            *(uint2*)(&As[(mg * 2 + j) * LDSTR + kg * 4]) = pk.v;
        }
        // ---- B-tile from prefetched regs ----
        *(h8*)(&Bs[brow * LDSTR + bkof]) = pb0;
        *(h8*)(&Bs[brow * LDSTR + bkof + 8]) = pb1;
        __syncthreads();

        // ---- Prefetch next B slice (drains under MFMA phase) ----
        int kn = k0 + 32;
        if (kn < 4096) {
            pb0 = *(const h8*)(bbase + kn);
            pb1 = *(const h8*)(bbase + kn + 8);
        }

        h8 af[4];
#pragma unroll
        for (int mt = 0; mt < 4; ++mt)
            af[mt] = *(const h8*)(&As[(wm + mt * 16 + fr_m) * LDSTR + khalf8]);
#pragma unroll
        for (int nt = 0; nt < 4; ++nt) {
            h8 bf = *(const h8*)(&Bs[(wn + nt * 16 + fr_m) * LDSTR + khalf8]);
#pragma unroll
            for (int mt = 0; mt < 4; ++mt)
                acc[mt][nt] = __builtin_amdgcn_mfma_f32_16x16x32_f16(af[mt], bf, acc[mt][nt], 0, 0, 0);
        }
        __syncthreads();
    }

#pragma unroll
    for (int mt = 0; mt < 4; ++mt) {
#pragma unroll
        for (int reg = 0; reg < 4; ++reg) {
            int gm = m0 + wm + mt * 16 + (lane >> 4) * 4 + reg;
            if (gm < NN) {
                unsigned char* orow = t2 + (size_t)gm * 1024 + n0c + wn + fr_m;
#pragma unroll
                for (int nt = 0; nt < 4; ++nt)
                    orow[nt * 16] = f2fp8(acc[mt][nt][reg]);
            }
        }
    }
}

// Generic MFMA GEMM (layer 3): C(fp8)[M,ldc] = A[M,lda](f16) @ Bt[N][K](f16)^T
// 128x128 tile, register-prefetched staging. 20.5 KB LDS -> 8 blocks/CU.
__global__ __launch_bounds__(256) void gemm_mfma(const f16* __restrict__ A, int lda,
                                                 const f16* __restrict__ Bt, int K,
                                                 unsigned char* __restrict__ C, int ldc,
                                                 int M) {
    __shared__ f16 As[128 * LDSTR] __attribute__((aligned(16)));
    __shared__ f16 Bs[128 * LDSTR] __attribute__((aligned(16)));
    int tid = threadIdx.x;
    int m0 = blockIdx.y * 128;
    int n0 = blockIdx.x * 128;

    int row = tid >> 1;
    int kof = (tid & 1) * 16;
    int am  = m0 + row;
    if (am > M - 1) am = M - 1;

    int lane   = tid & 63;
    int wv     = tid >> 6;
    int fr_m   = lane & 15;
    int khalf8 = (lane >> 4) * 8;

    const f16* abase = A + (size_t)am * lda + kof;
    const f16* bbase = Bt + (size_t)(n0 + row) * K + kof;

    h8 pa0 = *(const h8*)(abase);
    h8 pa1 = *(const h8*)(abase + 8);
    h8 pb0 = *(const h8*)(bbase);
    h8 pb1 = *(const h8*)(bbase + 8);

    f32x4 acc[2][8];
#pragma unroll
    for (int i = 0; i < 2; ++i)
#pragma unroll
        for (int j = 0; j < 8; ++j) acc[i][j] = (f32x4){0.f, 0.f, 0.f, 0.f};

    for (int k0 = 0; k0 < K; k0 += 32) {
        *(h8*)(&As[row * LDSTR + kof]) = pa0;
        *(h8*)(&As[row * LDSTR + kof + 8]) = pa1;
        *(h8*)(&Bs[row * LDSTR + kof]) = pb0;
        *(h8*)(&Bs[row * LDSTR + kof + 8]) = pb1;
        __syncthreads();

        int kn = k0 + 32;
        if (kn < K) {
            pa0 = *(const h8*)(abase + kn);
            pa1 = *(const h8*)(abase + kn + 8);
            pb0 = *(const h8*)(bbase + kn);
            pb1 = *(const h8*)(bbase + kn + 8);
        }

        h8 af0 = *(const h8*)(&As[(wv * 32 + fr_m) * LDSTR + khalf8]);
        h8 af1 = *(const h8*)(&As[(wv * 32 + 16 + fr_m) * LDSTR + khalf8]);
#pragma unroll
        for (int nt = 0; nt < 8; ++nt) {
            h8 bf = *(const h8*)(&Bs[(nt * 16 + fr_m) * LDSTR + khalf8]);
            acc[0][nt] = __builtin_amdgcn_mfma_f32_16x16x32_f16(af0, bf, acc[0][nt], 0, 0, 0);
            acc[1][nt] = __builtin_amdgcn_mfma_f32_16x16x32_f16(af1, bf, acc[1][nt], 0, 0, 0);
        }
        __syncthreads();
    }

#pragma unroll
    for (int mt = 0; mt < 2; ++mt) {
#pragma unroll
        for (int reg = 0; reg < 4; ++reg) {
            int gm = m0 + wv * 32 + mt * 16 + (lane >> 4) * 4 + reg;
            if (gm < M) {
                unsigned char* orow = C + (size_t)gm * ldc + n0 + fr_m;
#pragma unroll
                for (int nt = 0; nt < 8; ++nt)
                    orow[nt * 16] = f2fp8(acc[mt][nt][reg]);
            }
        }
    }
}

// ---------------------------------------------------------------------------
// Layer-4 GEMM: C[M,64] f32 = A[M,256](f16) @ B[256,64](f32)
// ---------------------------------------------------------------------------
#define BM 64
#define BN 64
#define BKS 16
__global__ __launch_bounds__(256) void gemm_f16A_kernel(const f16* __restrict__ A,
                                                        const float* __restrict__ B,
                                                        float* __restrict__ C,
                                                        int M, int K, int N) {
    __shared__ float As[BKS][BM + 4];
    __shared__ float Bs[BKS][BN + 4];
    int tid = threadIdx.x;
    int tx = tid & 15;
    int ty = tid >> 4;
    int m0 = blockIdx.y * BM;
    int n0 = blockIdx.x * BN;

    float acc[4][4];
#pragma unroll
    for (int i = 0; i < 4; ++i)
#pragma unroll
        for (int j = 0; j < 4; ++j) acc[i][j] = 0.f;

    int lmA = tid >> 2;
    int lkA = (tid & 3) * 4;
    int lkB = tid >> 4;
    int lnB = (tid & 15) * 4;

    for (int k0 = 0; k0 < K; k0 += BKS) {
        int gm = m0 + lmA;
        if (gm > M - 1) gm = M - 1;
        h4v av = *(const h4v*)(A + (size_t)gm * K + k0 + lkA);
        As[lkA + 0][lmA] = (float)av.x;
        As[lkA + 1][lmA] = (float)av.y;
        As[lkA + 2][lmA] = (float)av.z;
        As[lkA + 3][lmA] = (float)av.w;
        float4 bv = *reinterpret_cast<const float4*>(B + (size_t)(k0 + lkB) * N + n0 + lnB);
        *reinterpret_cast<float4*>(&Bs[lkB][lnB]) = bv;
        __syncthreads();

#pragma unroll
        for (int k = 0; k < BKS; ++k) {
            float4 a4 = *reinterpret_cast<const float4*>(&As[k][ty * 4]);
            float4 b4 = *reinterpret_cast<const float4*>(&Bs[k][tx * 4]);
            float a[4] = {a4.x, a4.y, a4.z, a4.w};
            float b[4] = {b4.x, b4.y, b4.z, b4.w};
#pragma unroll
            for (int i = 0; i < 4; ++i)
#pragma unroll
                for (int j = 0; j < 4; ++j) acc[i][j] += a[i] * b[j];
        }
        __syncthreads();
    }

#pragma unroll
    for (int i = 0; i < 4; ++i) {
        int m = m0 + ty * 4 + i;
        if (m < M) {
            float4 o = make_float4(acc[i][0], acc[i][1], acc[i][2], acc[i][3]);
            *reinterpret_cast<float4*>(C + (size_t)m * N + n0 + tx * 4) = o;
        }
    }
}

// Layer-5 GEMM: t5 = h4[NN,64](f16) @ W5[64,16](f32)
__global__ __launch_bounds__(256) void gemm5_kernel(const f16* __restrict__ h4,
                                                    const float* __restrict__ W5,
                                                    float* __restrict__ t5, int nNodes) {
    int idx = blockIdx.x * 256 + threadIdx.x;
    int i = idx >> 4, j = idx & 15;
    if (i >= nNodes) return;
    const f16* a = h4 + (size_t)i * 64;
    float s = 0.f;
#pragma unroll
    for (int k = 0; k < 64; ++k) s += (float)a[k] * W5[k * 16 + j];
    t5[idx] = s;
}

// Pool + classifier
__global__ __launch_bounds__(256) void pool_kernel(const float* __restrict__ h5,
                                                   float* __restrict__ pool) {
    __shared__ float red[256];
    int c = blockIdx.x;
    float s = 0.f;
    for (int i = threadIdx.x; i < NN; i += 256) s += h5[(size_t)i * 16 + c];
    red[threadIdx.x] = s;
    __syncthreads();
    for (int off = 128; off > 0; off >>= 1) {
        if ((int)threadIdx.x < off) red[threadIdx.x] += red[threadIdx.x + off];
        __syncthreads();
    }
    if (threadIdx.x == 0) pool[c] = red[0];
}

__global__ void final_kernel(const float* __restrict__ pool, const float* __restrict__ Wl,
                             const float* __restrict__ bl, float* __restrict__ out) {
    int j = threadIdx.x;
    if (j < 3) {
        float s = 0.f;
#pragma unroll
        for (int c = 0; c < 16; ++c) s += pool[c] * Wl[c * 3 + j];
        out[j] = s * (1.0f / (float)NN) + bl[j];
    }
}

// ---------------------------------------------------------------------------
// Host launcher — workspace ledger identical to rounds 7-13 (~205 MB, proven).
// ---------------------------------------------------------------------------
extern "C" void kernel_launch(void* const* d_in, const int* in_sizes, int n_in,
                              void* d_out, int out_size, void* d_ws, size_t ws_size,
                              hipStream_t stream) {
    (void)in_sizes; (void)n_in; (void)out_size; (void)ws_size;

    const float* x  = (const float*)d_in[0];
    const int*   ei = (const int*)d_in[1];
    const float* W1 = (const float*)d_in[2];
    const float* b1 = (const float*)d_in[3];
    const float* W2 = (const float*)d_in[4];
    const float* b2 = (const float*)d_in[5];
    const float* W3 = (const float*)d_in[6];
    const float* b3 = (const float*)d_in[7];
    const float* W4 = (const float*)d_in[8];
    const float* b4 = (const float*)d_in[9];
    const float* W5 = (const float*)d_in[10];
    const float* b5 = (const float*)d_in[11];
    const float* Wl = (const float*)d_in[12];
    const float* bl = (const float*)d_in[13];
    float* out = (float*)d_out;

    const int* srcp = ei;
    const int* dstp = ei + NE;

    char* p = (char*)d_ws;
    auto carve = [&](size_t bytes) {
        char* r = p;
        p += (bytes + 255) & ~(size_t)255;
        return r;
    };
    int*   deg  = (int*)carve(NN * 4);
    int*   cur  = (int*)carve(NN * 4);
    int*   rs   = (int*)carve((NN + 1) * 4);
    int*   bsum = (int*)carve(256 * 4);
    int*   csr  = (int*)carve((size_t)NE * 4);
    float* dinv = (float*)carve(NN * 4);
    float* aggx = (float*)carve((size_t)NN * 3 * 4);
    float* pool = (float*)carve(16 * 4);
    float* w1p  = (float*)carve((size_t)4096 * 4 * 4);       // 64 KB
    f16*   w2t  = (f16*)carve((size_t)1024 * 4096 * 2);      // 8.4 MB
    f16*   w3t  = (f16*)carve((size_t)256 * 1024 * 2);       // 0.5 MB
    unsigned char* tbuf = (unsigned char*)carve((size_t)NN * 1024);  // 51.2 MB: fp8 t2[NN,1024] / t3 / f32 t4,t5 view
    f16*   h2   = (f16*)carve((size_t)NN * 1024 * 2);        // 102.4 MB
    f16*   h3   = (f16*)carve((size_t)NN * 256 * 2);         // 25.6 MB
    f16*   h4   = (f16*)carve((size_t)NN * 64 * 2);          // 6.4 MB
    float* h5   = (float*)carve((size_t)NN * 16 * 4);        // 3.2 MB
    float* tf32 = (float*)tbuf;                              // f32 view for t4/t5

    const int NB = (NN + 255) / 256;  // 196

    zero_int_kernel<<<NB, 256, 0, stream>>>(deg, NN);
    zero_int_kernel<<<NB, 256, 0, stream>>>(cur, NN);
    count_kernel<<<(NE + 255) / 256, 256, 0, stream>>>(dstp, deg, NE);
    dinv_kernel<<<NB, 256, 0, stream>>>(deg, dinv, NN);
    scan1_kernel<<<NB, 256, 0, stream>>>(deg, rs, bsum, NN);
    scan2_kernel<<<1, 256, 0, stream>>>(bsum, rs, NB, NN);
    scan3_kernel<<<NB, 256, 0, stream>>>(rs, bsum, NN);
    fill_kernel<<<(NE + 255) / 256, 256, 0, stream>>>(srcp, dstp, rs, cur, csr, NE);

    // Weight prep
    pack_w1_kernel<<<16, 256, 0, stream>>>(W1, b1, w1p);
    tconv_kernel<<<dim3(1024 / 32, 4096 / 32), 256, 0, stream>>>(W2, w2t, 4096, 1024);
    tconv_kernel<<<dim3(256 / 32, 1024 / 32), 256, 0, stream>>>(W3, w3t, 1024, 256);

    // aggx = A_hat @ x (width 3, fp32)
    agg_kernel<3, 1, false, false, float><<<NB, 256, 0, stream>>>(
        x, dinv, rs, csr, nullptr, aggx, 3, NN);

    const int MB2 = (NN + 127) / 128;  // 391

    // Layers 1+2 fused: one 512-thread MFMA launch for all 1024 cols (fp8 out)
    gemm12_mfma4<<<dim3(MB2, 4), 512, 0, stream>>>(aggx, w1p, w2t, tbuf);
    // h2 = relu(A_hat t2 + b2): ONE pass, uint4/lane (16 B) per edge
    agg_fp8_1024<true><<<(NN + 3) / 4, 256, 0, stream>>>(
        tbuf, dinv, rs, csr, b2, h2, NN);

    // Layer 3 (MFMA, fp8 out): t3 = h2 @ W3; h3 = relu(A_hat t3 + b3)
    gemm_mfma<<<dim3(2, MB2), 256, 0, stream>>>(
        h2, 1024, w3t, 1024, tbuf, 256, NN);
    agg_fp8_256<true><<<(NN + 3) / 4, 256, 0, stream>>>(
        tbuf, 256, dinv, rs, csr, b3, h3, 256, NN);

    // Layer 4: t4 = h3 @ W4 [NN,64] f32; h4 = relu(A_hat t4 + b4) -> f16
    gemm_f16A_kernel<<<dim3(1, (NN + BM - 1) / BM), 256, 0, stream>>>(
        h3, W4, tf32, NN, 256, 64);
    agg_kernel<64, 64, true, true, f16><<<(NN + 3) / 4, 256, 0, stream>>>(
        tf32, dinv, rs, csr, b4, h4, 64, NN);

    // Layer 5: t5 = h4 @ W5 [NN,16] f32; h5 = A_hat t5 + b5 (no relu)
    gemm5_kernel<<<(NN * 16 + 255) / 256, 256, 0, stream>>>(h4, W5, tf32, NN);
    agg_kernel<16, 16, false, true, float><<<(NN + 15) / 16, 256, 0, stream>>>(
        tf32, dinv, rs, csr, b5, h5, 16, NN);

    // Global mean pool + classifier
    pool_kernel<<<16, 256, 0, stream>>>(h5, pool);
    final_kernel<<<1, 64, 0, stream>>>(pool, Wl, bl, out);
}